// Round 11
// baseline (544.822 us; speedup 1.0000x reference)
//
#include <hip/hip_runtime.h>
#include <math.h>

#define N_NODES 100000
#define NNZ_E   3200000
#define NFEAT   512
#define NHID    256
#define NCLASS  41
#define NC_PAD  48     // w2t padded rows
#define P_STRIDE 64    // p row stride in bytes (fp8)

typedef __attribute__((ext_vector_type(8))) short   short8;   // 8 bf16 (4 VGPRs)
typedef __attribute__((ext_vector_type(4))) float   f32x4;
typedef __attribute__((ext_vector_type(2))) float   f32x2;

typedef __attribute__((address_space(1))) const unsigned int gu32;
typedef __attribute__((address_space(3))) unsigned int lu32;

// ---- bf16 helpers ----
__device__ __forceinline__ unsigned short f2bf(float f) {
    unsigned u = __builtin_bit_cast(unsigned, f);
    unsigned r = u + 0x7fffu + ((u >> 16) & 1u);   // RNE
    return (unsigned short)(r >> 16);
}
// ---- fp8 e4m3 helpers (OCP, native gfx950 cvt) ----
__device__ __forceinline__ unsigned char f2fp8(float f) {
    return (unsigned char)(__builtin_amdgcn_cvt_pk_fp8_f32(f, 0.f, 0, false) & 0xff);
}
__device__ __forceinline__ unsigned pk4(float a, float b, float c, float d) {
    unsigned u = __builtin_amdgcn_cvt_pk_fp8_f32(a, b, 0, false);
    return (unsigned)__builtin_amdgcn_cvt_pk_fp8_f32(c, d, (int)u, true);
}

// ---------------------------------------------------------------------------
// K0 (merged): CSR row_ptr + w1q fp8 + w2t bf16.
// Block ranges: [0,392) rowptr | [392,904) w1q | [904,952) w2t
// ---------------------------------------------------------------------------
__global__ __launch_bounds__(256) void prep_misc_kernel(const int* __restrict__ rows,
                                                        const float* __restrict__ w1,
                                                        const float* __restrict__ w2,
                                                        int* __restrict__ row_ptr,
                                                        unsigned char* __restrict__ w1q,
                                                        unsigned short* __restrict__ w2t) {
    int b = blockIdx.x;
    if (b < 392) {
        int r = b * 256 + threadIdx.x;
        if (r > N_NODES) return;
        int lo = 0, hi = NNZ_E;
        while (lo < hi) {
            int mid = (lo + hi) >> 1;
            if (rows[mid] < r) lo = mid + 1; else hi = mid;
        }
        row_ptr[r] = lo;
        return;
    }
    b -= 392;
    if (b < 512) {
        int tid = b * 256 + threadIdx.x;   // < 131072 exactly
        int n = tid >> 9, k = tid & 511;
        w1q[tid] = f2fp8(w1[k * NHID + n]);
        return;
    }
    b -= 512;
    {
        int t2 = b * 256 + threadIdx.x;    // < 12288 exactly
        int n = t2 >> 8, k = t2 & 255;
        w2t[t2] = (n < NCLASS) ? f2bf(w2[k * NCLASS + n]) : (unsigned short)0;
    }
}

// ---------------------------------------------------------------------------
// K1: fused quantize + GEMM:  xw = fp8(x) @ w1q  -> fp8 [N,256] row-major.
// 128-row x 256-col block tile (full N internal), BK=64, 512 threads / 8 waves.
// (r4 proven single-buffer version)
// ---------------------------------------------------------------------------
__global__ __launch_bounds__(512) void gemm1_kernel(const float* __restrict__ x,
                                                    const unsigned char* __restrict__ w1q,
                                                    unsigned char* __restrict__ xw) {
    __shared__ unsigned char As[8192];    // 128 rows x 64 B (swizzled)
    __shared__ unsigned char Bs[16384];   // 256 n    x 64 B (swizzled)

    const int tid  = threadIdx.x;
    const int wv   = tid >> 6;          // 0..7
    const int lane = tid & 63;
    const int l15  = lane & 15;
    const int quad = lane >> 4;
    const int wvM  = wv >> 2;           // 0..1  (row half)
    const int wvN  = wv & 3;            // 0..3  (col quarter)
    const int rb   = blockIdx.x * 128;

    const int ar = tid >> 2;            // 0..127
    const int aq = tid & 3;             // 0..3
    int arow = rb + ar; if (arow >= N_NODES) arow = N_NODES - 1;
    const float* asrc = x + (long)arow * NFEAT + aq * 16;
    unsigned char* adst0 = As + ar * 64 + (((2 * aq + 0) ^ (ar & 6)) * 8);
    unsigned char* adst1 = As + ar * 64 + (((2 * aq + 1) ^ (ar & 6)) * 8);

    const int bn0 = (wv * 2 + 0) * 16 + (lane >> 2);
    const int bn1 = (wv * 2 + 1) * 16 + (lane >> 2);
    const int bg0 = (lane & 3) ^ ((bn0 >> 1) & 3);
    const int bg1 = (lane & 3) ^ ((bn1 >> 1) & 3);
    const unsigned char* bsrc0 = w1q + (long)bn0 * NFEAT + bg0 * 16;
    const unsigned char* bsrc1 = w1q + (long)bn1 * NFEAT + bg1 * 16;

    f32x4 acc[4][4] = {};

    float4 fr0 = *(const float4*)(asrc);
    float4 fr1 = *(const float4*)(asrc + 4);
    float4 fr2 = *(const float4*)(asrc + 8);
    float4 fr3 = *(const float4*)(asrc + 12);

    for (int c = 0; c < 8; c++) {
        const int kc = c * 64;
        __builtin_amdgcn_global_load_lds((gu32*)(bsrc0 + kc), (lu32*)(Bs + (wv * 2 + 0) * 1024), 16, 0, 0);
        __builtin_amdgcn_global_load_lds((gu32*)(bsrc1 + kc), (lu32*)(Bs + (wv * 2 + 1) * 1024), 16, 0, 0);
        unsigned u0 = pk4(fr0.x, fr0.y, fr0.z, fr0.w);
        unsigned u1 = pk4(fr1.x, fr1.y, fr1.z, fr1.w);
        unsigned u2 = pk4(fr2.x, fr2.y, fr2.z, fr2.w);
        unsigned u3 = pk4(fr3.x, fr3.y, fr3.z, fr3.w);
        *(unsigned long long*)adst0 = (unsigned long long)u0 | ((unsigned long long)u1 << 32);
        *(unsigned long long*)adst1 = (unsigned long long)u2 | ((unsigned long long)u3 << 32);
        if (c < 7) {
            fr0 = *(const float4*)(asrc + kc + 64);
            fr1 = *(const float4*)(asrc + kc + 68);
            fr2 = *(const float4*)(asrc + kc + 72);
            fr3 = *(const float4*)(asrc + kc + 76);
        }
        __syncthreads();

        unsigned long long a[4][2], b[4][2];
#pragma unroll
        for (int mt = 0; mt < 4; mt++) {
            int row = wvM * 64 + mt * 16 + l15;
#pragma unroll
            for (int ks = 0; ks < 2; ks++) {
                int p8 = (ks * 4 + quad) ^ (row & 6);
                a[mt][ks] = *(const unsigned long long*)(As + row * 64 + p8 * 8);
            }
        }
#pragma unroll
        for (int nt = 0; nt < 4; nt++) {
            int nr = wvN * 64 + nt * 16 + l15;
#pragma unroll
            for (int ks = 0; ks < 2; ks++) {
                int p8 = (ks * 4 + quad) ^ (nr & 6);
                b[nt][ks] = *(const unsigned long long*)(Bs + nr * 64 + p8 * 8);
            }
        }
#pragma unroll
        for (int ks = 0; ks < 2; ks++)
#pragma unroll
            for (int nt = 0; nt < 4; nt++)
#pragma unroll
                for (int mt = 0; mt < 4; mt++)
                    acc[mt][nt] = __builtin_amdgcn_mfma_f32_16x16x32_fp8_fp8(
                        (long)a[mt][ks], (long)b[nt][ks], acc[mt][nt], 0, 0, 0);
        __syncthreads();
    }

#pragma unroll
    for (int mt = 0; mt < 4; mt++) {
        int row0 = rb + wvM * 64 + mt * 16 + quad * 4;
#pragma unroll
        for (int nt = 0; nt < 4; nt++) {
            int col = wvN * 64 + nt * 16 + l15;
#pragma unroll
            for (int r = 0; r < 4; r++) {
                int row = row0 + r;
                if (row < N_NODES)
                    xw[(long)row * NHID + col] = f2fp8(acc[mt][nt][r]);
            }
        }
    }
}

// ---------------------------------------------------------------------------
// K2 (fused spmm1 + gemm2): p = relu(spmm(A, xw) + b1) @ w2 -> fp8 [N,64].
// 16 rows/block (grid 6250, exact), 4 waves x 4 rows serial, LDS 8.4 KB.
// r11: 32-DEEP gather tier (was 16) — r10 confirmed the latency-MLP theory
// (8->16 deep = 134.5->123 us, VGPR only 40). A Poisson(32)-degree row now
// completes its gathers in ~1 deep block; consumption (~384 cyc) ~ covers
// gather latency. Tiers: 32 -> 8 -> scalar. launch_bounds(256,4) caps
// VGPR at 128 (expected ~110-120 live).
// Phase 2: wave 0 runs the single 16-row MFMA tile.
// ---------------------------------------------------------------------------
__global__ __launch_bounds__(256, 4) void spmm1g_kernel(const unsigned char* __restrict__ xw,
                                                        const int* __restrict__ row_ptr,
                                                        const int* __restrict__ cols,
                                                        const float* __restrict__ vals,
                                                        const float* __restrict__ b1,
                                                        const unsigned short* __restrict__ w2t,
                                                        unsigned char* __restrict__ p) {
    __shared__ unsigned short hl[16][264];

    const int wv   = threadIdx.x >> 6;
    const int lane = threadIdx.x & 63;
    const int row0 = blockIdx.x * 16;
    const float4 bv = *(const float4*)(b1 + lane * 4);

    for (int r = 0; r < 4; r++) {
        const int lrow = wv * 4 + r;
        const int row  = row0 + lrow;              // always < N_NODES (exact grid)
        int e0 = row_ptr[row], e1 = row_ptr[row + 1];

        float a0 = 0.f, a1 = 0.f, a2 = 0.f, a3 = 0.f;
        for (int base = e0; base < e1; base += 64) {
            int   myc = 0;
            float myv = 0.f;
            int idx = base + lane;
            if (idx < e1) { myc = cols[idx]; myv = vals[idx]; }
            int cnt = e1 - base; if (cnt > 64) cnt = 64;
            int j = 0;
            // 32-deep tier: 32 gathers in flight
            for (; j + 32 <= cnt; j += 32) {
                int c[32]; float v[32];
#pragma unroll
                for (int u = 0; u < 32; u++) { c[u] = __shfl(myc, j + u); v[u] = __shfl(myv, j + u); }
                unsigned q[32];
#pragma unroll
                for (int u = 0; u < 32; u++) q[u] = *(const unsigned*)(xw + (long)c[u] * NHID + lane * 4);
#pragma unroll
                for (int u = 0; u < 32; u++) {
                    f32x2 lo = __builtin_amdgcn_cvt_pk_f32_fp8((int)q[u], false);
                    f32x2 hi = __builtin_amdgcn_cvt_pk_f32_fp8((int)q[u], true);
                    a0 += v[u] * lo[0];
                    a1 += v[u] * lo[1];
                    a2 += v[u] * hi[0];
                    a3 += v[u] * hi[1];
                }
            }
            // 8-deep tier
            for (; j + 8 <= cnt; j += 8) {
                int c[8]; float v[8];
#pragma unroll
                for (int u = 0; u < 8; u++) { c[u] = __shfl(myc, j + u); v[u] = __shfl(myv, j + u); }
                unsigned q[8];
#pragma unroll
                for (int u = 0; u < 8; u++) q[u] = *(const unsigned*)(xw + (long)c[u] * NHID + lane * 4);
#pragma unroll
                for (int u = 0; u < 8; u++) {
                    f32x2 lo = __builtin_amdgcn_cvt_pk_f32_fp8((int)q[u], false);
                    f32x2 hi = __builtin_amdgcn_cvt_pk_f32_fp8((int)q[u], true);
                    a0 += v[u] * lo[0];
                    a1 += v[u] * lo[1];
                    a2 += v[u] * hi[0];
                    a3 += v[u] * hi[1];
                }
            }
            // scalar tail
            for (; j < cnt; j++) {
                int   c = __shfl(myc, j);
                float v = __shfl(myv, j);
                unsigned q = *(const unsigned*)(xw + (long)c * NHID + lane * 4);
                f32x2 lo = __builtin_amdgcn_cvt_pk_f32_fp8((int)q, false);
                f32x2 hi = __builtin_amdgcn_cvt_pk_f32_fp8((int)q, true);
                a0 += v * lo[0];
                a1 += v * lo[1];
                a2 += v * hi[0];
                a3 += v * hi[1];
            }
        }
        a0 = fmaxf(a0 + bv.x, 0.f);
        a1 = fmaxf(a1 + bv.y, 0.f);
        a2 = fmaxf(a2 + bv.z, 0.f);
        a3 = fmaxf(a3 + bv.w, 0.f);
        unsigned lo32 = (unsigned)f2bf(a0) | ((unsigned)f2bf(a1) << 16);
        unsigned hi32 = (unsigned)f2bf(a2) | ((unsigned)f2bf(a3) << 16);
        unsigned* dst = (unsigned*)&hl[lrow][lane * 4];
        dst[0] = lo32;
        dst[1] = hi32;
    }
    __syncthreads();

    if (wv == 0) {
        const int l15 = lane & 15, quad = lane >> 4;
        f32x4 acc[3] = {};
#pragma unroll
        for (int kc = 0; kc < NHID; kc += 32) {
            short8 a = *(const short8*)(&hl[l15][kc + quad * 8]);
#pragma unroll
            for (int nt = 0; nt < 3; nt++) {
                short8 b = *(const short8*)(w2t + (long)(nt * 16 + l15) * NHID + kc + quad * 8);
                acc[nt] = __builtin_amdgcn_mfma_f32_16x16x32_bf16(a, b, acc[nt], 0, 0, 0);
            }
        }
        const int prow0 = row0 + quad * 4;
#pragma unroll
        for (int nt = 0; nt < 3; nt++) {
            int col = nt * 16 + l15;
#pragma unroll
            for (int r = 0; r < 4; r++)
                p[(long)(prow0 + r) * P_STRIDE + col] = f2fp8(acc[nt][r]);
        }
    }
}

// ---------------------------------------------------------------------------
// K3: out = log_softmax(spmm(A, p) + b2).  One wave per row.
// p is fp8, 64 B rows (48 valid). e = lane>>4 (4 edges in flight),
// t = lane&15 (t<12 loads uint = cols 4t..4t+3). Direct same-address
// broadcast loads of cols/vals per 16-lane group (no shfl), 2-deep pipeline.
// ---------------------------------------------------------------------------
__global__ __launch_bounds__(256) void spmm2_kernel(const unsigned char* __restrict__ p,
                                                    const int* __restrict__ row_ptr,
                                                    const int* __restrict__ cols,
                                                    const float* __restrict__ vals,
                                                    const float* __restrict__ b2,
                                                    float* __restrict__ out) {
    int row = blockIdx.x * 4 + (threadIdx.x >> 6);
    if (row >= N_NODES) return;
    int lane = threadIdx.x & 63;
    int e = lane >> 4;          // edge sub-group 0..3
    int t = lane & 15;          // class chunk; t<12 active for loads
    int e0 = __builtin_amdgcn_readfirstlane(row_ptr[row]);
    int e1 = __builtin_amdgcn_readfirstlane(row_ptr[row + 1]);
    const unsigned toff = (unsigned)(t << 2);

    float a0 = 0.f, a1 = 0.f, a2 = 0.f, a3 = 0.f;
    if (e0 < e1) {
        const int em1 = e1 - 1;
        int i0 = e0 + e;     int i0c = i0 < e1 ? i0 : em1;
        int i1 = e0 + 4 + e; int i1c = i1 < e1 ? i1 : em1;
        int   ca = __builtin_nontemporal_load(cols + i0c);
        float va = __builtin_nontemporal_load(vals + i0c);
        int   cb = __builtin_nontemporal_load(cols + i1c);
        float vb = __builtin_nontemporal_load(vals + i1c);
        for (int j = e0; j < e1; j += 8) {
            int n0 = j + 8 + e;  int n0c = n0 < e1 ? n0 : em1;
            int n1 = j + 12 + e; int n1c = n1 < e1 ? n1 : em1;
            int   cc = __builtin_nontemporal_load(cols + n0c);
            float vc = __builtin_nontemporal_load(vals + n0c);
            int   cd = __builtin_nontemporal_load(cols + n1c);
            float vd = __builtin_nontemporal_load(vals + n1c);
            unsigned q0 = (t < 12) ? *(const unsigned*)(p + (long)ca * P_STRIDE + toff) : 0u;
            unsigned q1 = (t < 12) ? *(const unsigned*)(p + (long)cb * P_STRIDE + toff) : 0u;
            float v0 = (j + e     < e1) ? va : 0.f;
            float v1 = (j + 4 + e < e1) ? vb : 0.f;
            f32x2 lo0 = __builtin_amdgcn_cvt_pk_f32_fp8((int)q0, false);
            f32x2 hi0 = __builtin_amdgcn_cvt_pk_f32_fp8((int)q0, true);
            f32x2 lo1 = __builtin_amdgcn_cvt_pk_f32_fp8((int)q1, false);
            f32x2 hi1 = __builtin_amdgcn_cvt_pk_f32_fp8((int)q1, true);
            a0 += v0 * lo0[0]; a1 += v0 * lo0[1]; a2 += v0 * hi0[0]; a3 += v0 * hi0[1];
            a0 += v1 * lo1[0]; a1 += v1 * lo1[1]; a2 += v1 * hi1[0]; a3 += v1 * hi1[1];
            ca = cc; va = vc; cb = cd; vb = vd;
        }
    }
    // fold the 4 edge sub-groups (lanes with same t share class columns)
    a0 += __shfl_xor(a0, 16); a1 += __shfl_xor(a1, 16);
    a2 += __shfl_xor(a2, 16); a3 += __shfl_xor(a3, 16);
    a0 += __shfl_xor(a0, 32); a1 += __shfl_xor(a1, 32);
    a2 += __shfl_xor(a2, 32); a3 += __shfl_xor(a3, 32);

    int c0 = 4 * t, c1 = 4 * t + 1, c2 = 4 * t + 2, c3 = 4 * t + 3;
    float l0 = (c0 < NCLASS) ? a0 + b2[c0] : -__builtin_inff();
    float l1 = (c1 < NCLASS) ? a1 + b2[c1] : -__builtin_inff();
    float l2 = (c2 < NCLASS) ? a2 + b2[c2] : -__builtin_inff();
    float l3 = (c3 < NCLASS) ? a3 + b2[c3] : -__builtin_inff();
    float m = fmaxf(fmaxf(l0, l1), fmaxf(l2, l3));
#pragma unroll
    for (int s = 8; s; s >>= 1) m = fmaxf(m, __shfl_xor(m, s));
    float esum = ((c0 < NCLASS) ? __expf(l0 - m) : 0.f)
               + ((c1 < NCLASS) ? __expf(l1 - m) : 0.f)
               + ((c2 < NCLASS) ? __expf(l2 - m) : 0.f)
               + ((c3 < NCLASS) ? __expf(l3 - m) : 0.f);
#pragma unroll
    for (int s = 8; s; s >>= 1) esum += __shfl_xor(esum, s);
    float lse = m + __logf(esum);
    if (e == 0) {
        long ob = (long)row * NCLASS;
        if (c0 < NCLASS) out[ob + c0] = l0 - lse;
        if (c1 < NCLASS) out[ob + c1] = l1 - lse;
        if (c2 < NCLASS) out[ob + c2] = l2 - lse;
        if (c3 < NCLASS) out[ob + c3] = l3 - lse;
    }
}

// ---------------------------------------------------------------------------
extern "C" void kernel_launch(void* const* d_in, const int* in_sizes, int n_in,
                              void* d_out, int out_size, void* d_ws, size_t ws_size,
                              hipStream_t stream) {
    const float* x        = (const float*)d_in[0];
    const int*   adj_rows = (const int*)  d_in[1];
    const int*   adj_cols = (const int*)  d_in[2];
    const float* adj_vals = (const float*)d_in[3];
    const float* w1       = (const float*)d_in[4];
    const float* b1       = (const float*)d_in[5];
    const float* w2       = (const float*)d_in[6];
    const float* b2       = (const float*)d_in[7];
    float* out = (float*)d_out;

    // workspace layout (within the proven 78 MB footprint):
    //   p  at 0x90000   (6.4 MB fp8 [N,64], spmm1g->spmm2; must NOT alias xw)
    //   xw at 0x3180000 (25.6 MB fp8 [N,256], gemm1->spmm1g)
    char* ws = (char*)d_ws;
    unsigned char*  w1q     = (unsigned char*) (ws);                  // 128 KB
    unsigned short* w2t     = (unsigned short*)(ws + 0x20000);        // 24 KB
    int*            row_ptr = (int*)           (ws + 0x26000);        // 0.4 MB
    unsigned char*  p       = (unsigned char*) (ws + 0x90000);        // 6.4 MB
    unsigned char*  xw      = (unsigned char*) (ws + 0x3180000);      // 25.6 MB

    prep_misc_kernel<<<392 + 512 + 48, 256, 0, stream>>>(adj_rows, w1, w2, row_ptr, w1q, w2t);
    gemm1_kernel<<<(N_NODES + 127) / 128, 512, 0, stream>>>(x, w1q, xw);
    spmm1g_kernel<<<N_NODES / 16, 256, 0, stream>>>(xw, row_ptr, adj_cols, adj_vals, b1, w2t, p);
    spmm2_kernel<<<(N_NODES + 3) / 4, 256, 0, stream>>>(p, row_ptr, adj_cols, adj_vals, b2, out);
}

// Round 12
// 533.551 us; speedup vs baseline: 1.0211x; 1.0211x over previous
//
#include <hip/hip_runtime.h>
#include <math.h>

#define N_NODES 100000
#define NNZ_E   3200000
#define NFEAT   512
#define NHID    256
#define NCLASS  41
#define NC_PAD  48     // w2t padded rows
#define P_STRIDE 64    // p row stride in bytes (fp8)

typedef __attribute__((ext_vector_type(8))) short   short8;   // 8 bf16 (4 VGPRs)
typedef __attribute__((ext_vector_type(4))) float   f32x4;
typedef __attribute__((ext_vector_type(2))) float   f32x2;

typedef __attribute__((address_space(1))) const unsigned int gu32;
typedef __attribute__((address_space(3))) unsigned int lu32;

// ---- bf16 helpers ----
__device__ __forceinline__ unsigned short f2bf(float f) {
    unsigned u = __builtin_bit_cast(unsigned, f);
    unsigned r = u + 0x7fffu + ((u >> 16) & 1u);   // RNE
    return (unsigned short)(r >> 16);
}
// ---- fp8 e4m3 helpers (OCP, native gfx950 cvt) ----
__device__ __forceinline__ unsigned char f2fp8(float f) {
    return (unsigned char)(__builtin_amdgcn_cvt_pk_fp8_f32(f, 0.f, 0, false) & 0xff);
}
__device__ __forceinline__ unsigned pk4(float a, float b, float c, float d) {
    unsigned u = __builtin_amdgcn_cvt_pk_fp8_f32(a, b, 0, false);
    return (unsigned)__builtin_amdgcn_cvt_pk_fp8_f32(c, d, (int)u, true);
}

// ---------------------------------------------------------------------------
// K0 (merged): CSR row_ptr + w1q fp8 + w2t bf16.
// Block ranges: [0,392) rowptr | [392,904) w1q | [904,952) w2t
// ---------------------------------------------------------------------------
__global__ __launch_bounds__(256) void prep_misc_kernel(const int* __restrict__ rows,
                                                        const float* __restrict__ w1,
                                                        const float* __restrict__ w2,
                                                        int* __restrict__ row_ptr,
                                                        unsigned char* __restrict__ w1q,
                                                        unsigned short* __restrict__ w2t) {
    int b = blockIdx.x;
    if (b < 392) {
        int r = b * 256 + threadIdx.x;
        if (r > N_NODES) return;
        int lo = 0, hi = NNZ_E;
        while (lo < hi) {
            int mid = (lo + hi) >> 1;
            if (rows[mid] < r) lo = mid + 1; else hi = mid;
        }
        row_ptr[r] = lo;
        return;
    }
    b -= 392;
    if (b < 512) {
        int tid = b * 256 + threadIdx.x;   // < 131072 exactly
        int n = tid >> 9, k = tid & 511;
        w1q[tid] = f2fp8(w1[k * NHID + n]);
        return;
    }
    b -= 512;
    {
        int t2 = b * 256 + threadIdx.x;    // < 12288 exactly
        int n = t2 >> 8, k = t2 & 255;
        w2t[t2] = (n < NCLASS) ? f2bf(w2[k * NCLASS + n]) : (unsigned short)0;
    }
}

// ---------------------------------------------------------------------------
// K1: fused quantize + GEMM:  xw = fp8(x) @ w1q  -> fp8 [N,256] row-major.
// 128-row x 256-col block tile (full N internal), BK=64, 512 threads / 8 waves.
// (r4 proven single-buffer version)
// ---------------------------------------------------------------------------
__global__ __launch_bounds__(512) void gemm1_kernel(const float* __restrict__ x,
                                                    const unsigned char* __restrict__ w1q,
                                                    unsigned char* __restrict__ xw) {
    __shared__ unsigned char As[8192];    // 128 rows x 64 B (swizzled)
    __shared__ unsigned char Bs[16384];   // 256 n    x 64 B (swizzled)

    const int tid  = threadIdx.x;
    const int wv   = tid >> 6;          // 0..7
    const int lane = tid & 63;
    const int l15  = lane & 15;
    const int quad = lane >> 4;
    const int wvM  = wv >> 2;           // 0..1  (row half)
    const int wvN  = wv & 3;            // 0..3  (col quarter)
    const int rb   = blockIdx.x * 128;

    const int ar = tid >> 2;            // 0..127
    const int aq = tid & 3;             // 0..3
    int arow = rb + ar; if (arow >= N_NODES) arow = N_NODES - 1;
    const float* asrc = x + (long)arow * NFEAT + aq * 16;
    unsigned char* adst0 = As + ar * 64 + (((2 * aq + 0) ^ (ar & 6)) * 8);
    unsigned char* adst1 = As + ar * 64 + (((2 * aq + 1) ^ (ar & 6)) * 8);

    const int bn0 = (wv * 2 + 0) * 16 + (lane >> 2);
    const int bn1 = (wv * 2 + 1) * 16 + (lane >> 2);
    const int bg0 = (lane & 3) ^ ((bn0 >> 1) & 3);
    const int bg1 = (lane & 3) ^ ((bn1 >> 1) & 3);
    const unsigned char* bsrc0 = w1q + (long)bn0 * NFEAT + bg0 * 16;
    const unsigned char* bsrc1 = w1q + (long)bn1 * NFEAT + bg1 * 16;

    f32x4 acc[4][4] = {};

    float4 fr0 = *(const float4*)(asrc);
    float4 fr1 = *(const float4*)(asrc + 4);
    float4 fr2 = *(const float4*)(asrc + 8);
    float4 fr3 = *(const float4*)(asrc + 12);

    for (int c = 0; c < 8; c++) {
        const int kc = c * 64;
        __builtin_amdgcn_global_load_lds((gu32*)(bsrc0 + kc), (lu32*)(Bs + (wv * 2 + 0) * 1024), 16, 0, 0);
        __builtin_amdgcn_global_load_lds((gu32*)(bsrc1 + kc), (lu32*)(Bs + (wv * 2 + 1) * 1024), 16, 0, 0);
        unsigned u0 = pk4(fr0.x, fr0.y, fr0.z, fr0.w);
        unsigned u1 = pk4(fr1.x, fr1.y, fr1.z, fr1.w);
        unsigned u2 = pk4(fr2.x, fr2.y, fr2.z, fr2.w);
        unsigned u3 = pk4(fr3.x, fr3.y, fr3.z, fr3.w);
        *(unsigned long long*)adst0 = (unsigned long long)u0 | ((unsigned long long)u1 << 32);
        *(unsigned long long*)adst1 = (unsigned long long)u2 | ((unsigned long long)u3 << 32);
        if (c < 7) {
            fr0 = *(const float4*)(asrc + kc + 64);
            fr1 = *(const float4*)(asrc + kc + 68);
            fr2 = *(const float4*)(asrc + kc + 72);
            fr3 = *(const float4*)(asrc + kc + 76);
        }
        __syncthreads();

        unsigned long long a[4][2], b[4][2];
#pragma unroll
        for (int mt = 0; mt < 4; mt++) {
            int row = wvM * 64 + mt * 16 + l15;
#pragma unroll
            for (int ks = 0; ks < 2; ks++) {
                int p8 = (ks * 4 + quad) ^ (row & 6);
                a[mt][ks] = *(const unsigned long long*)(As + row * 64 + p8 * 8);
            }
        }
#pragma unroll
        for (int nt = 0; nt < 4; nt++) {
            int nr = wvN * 64 + nt * 16 + l15;
#pragma unroll
            for (int ks = 0; ks < 2; ks++) {
                int p8 = (ks * 4 + quad) ^ (nr & 6);
                b[nt][ks] = *(const unsigned long long*)(Bs + nr * 64 + p8 * 8);
            }
        }
#pragma unroll
        for (int ks = 0; ks < 2; ks++)
#pragma unroll
            for (int nt = 0; nt < 4; nt++)
#pragma unroll
                for (int mt = 0; mt < 4; mt++)
                    acc[mt][nt] = __builtin_amdgcn_mfma_f32_16x16x32_fp8_fp8(
                        (long)a[mt][ks], (long)b[nt][ks], acc[mt][nt], 0, 0, 0);
        __syncthreads();
    }

#pragma unroll
    for (int mt = 0; mt < 4; mt++) {
        int row0 = rb + wvM * 64 + mt * 16 + quad * 4;
#pragma unroll
        for (int nt = 0; nt < 4; nt++) {
            int col = wvN * 64 + nt * 16 + l15;
#pragma unroll
            for (int r = 0; r < 4; r++) {
                int row = row0 + r;
                if (row < N_NODES)
                    xw[(long)row * NHID + col] = f2fp8(acc[mt][nt][r]);
            }
        }
    }
}

// ---------------------------------------------------------------------------
// K2 (fused spmm1 + gemm2): p = relu(spmm(A, xw) + b1) @ w2 -> fp8 [N,64].
// 16 rows/block (grid 6250, exact), 4 waves x 4 rows serial, LDS 8.4 KB.
// r12: EXACT r10 inner loop (16-deep tier) — r10 measured best (123 us,
// occ 55%); r11's 32-deep regressed (131 us, occ 49%: 32-shfl serial
// prologue + coarser tier granularity). Tiers: 16 -> 8 -> scalar.
// __launch_bounds__(256,4). Phase 2: wave 0 runs the 16-row MFMA tile.
// ---------------------------------------------------------------------------
__global__ __launch_bounds__(256, 4) void spmm1g_kernel(const unsigned char* __restrict__ xw,
                                                        const int* __restrict__ row_ptr,
                                                        const int* __restrict__ cols,
                                                        const float* __restrict__ vals,
                                                        const float* __restrict__ b1,
                                                        const unsigned short* __restrict__ w2t,
                                                        unsigned char* __restrict__ p) {
    __shared__ unsigned short hl[16][264];

    const int wv   = threadIdx.x >> 6;
    const int lane = threadIdx.x & 63;
    const int row0 = blockIdx.x * 16;
    const float4 bv = *(const float4*)(b1 + lane * 4);

    for (int r = 0; r < 4; r++) {
        const int lrow = wv * 4 + r;
        const int row  = row0 + lrow;              // always < N_NODES (exact grid)
        int e0 = row_ptr[row], e1 = row_ptr[row + 1];

        float a0 = 0.f, a1 = 0.f, a2 = 0.f, a3 = 0.f;
        for (int base = e0; base < e1; base += 64) {
            int   myc = 0;
            float myv = 0.f;
            int idx = base + lane;
            if (idx < e1) { myc = cols[idx]; myv = vals[idx]; }
            int cnt = e1 - base; if (cnt > 64) cnt = 64;
            int j = 0;
            // 16-deep tier: 16 gathers in flight
            for (; j + 16 <= cnt; j += 16) {
                int c[16]; float v[16];
#pragma unroll
                for (int u = 0; u < 16; u++) { c[u] = __shfl(myc, j + u); v[u] = __shfl(myv, j + u); }
                unsigned q[16];
#pragma unroll
                for (int u = 0; u < 16; u++) q[u] = *(const unsigned*)(xw + (long)c[u] * NHID + lane * 4);
#pragma unroll
                for (int u = 0; u < 16; u++) {
                    f32x2 lo = __builtin_amdgcn_cvt_pk_f32_fp8((int)q[u], false);
                    f32x2 hi = __builtin_amdgcn_cvt_pk_f32_fp8((int)q[u], true);
                    a0 += v[u] * lo[0];
                    a1 += v[u] * lo[1];
                    a2 += v[u] * hi[0];
                    a3 += v[u] * hi[1];
                }
            }
            // 8-deep tier
            for (; j + 8 <= cnt; j += 8) {
                int c[8]; float v[8];
#pragma unroll
                for (int u = 0; u < 8; u++) { c[u] = __shfl(myc, j + u); v[u] = __shfl(myv, j + u); }
                unsigned q[8];
#pragma unroll
                for (int u = 0; u < 8; u++) q[u] = *(const unsigned*)(xw + (long)c[u] * NHID + lane * 4);
#pragma unroll
                for (int u = 0; u < 8; u++) {
                    f32x2 lo = __builtin_amdgcn_cvt_pk_f32_fp8((int)q[u], false);
                    f32x2 hi = __builtin_amdgcn_cvt_pk_f32_fp8((int)q[u], true);
                    a0 += v[u] * lo[0];
                    a1 += v[u] * lo[1];
                    a2 += v[u] * hi[0];
                    a3 += v[u] * hi[1];
                }
            }
            // scalar tail
            for (; j < cnt; j++) {
                int   c = __shfl(myc, j);
                float v = __shfl(myv, j);
                unsigned q = *(const unsigned*)(xw + (long)c * NHID + lane * 4);
                f32x2 lo = __builtin_amdgcn_cvt_pk_f32_fp8((int)q, false);
                f32x2 hi = __builtin_amdgcn_cvt_pk_f32_fp8((int)q, true);
                a0 += v * lo[0];
                a1 += v * lo[1];
                a2 += v * hi[0];
                a3 += v * hi[1];
            }
        }
        a0 = fmaxf(a0 + bv.x, 0.f);
        a1 = fmaxf(a1 + bv.y, 0.f);
        a2 = fmaxf(a2 + bv.z, 0.f);
        a3 = fmaxf(a3 + bv.w, 0.f);
        unsigned lo32 = (unsigned)f2bf(a0) | ((unsigned)f2bf(a1) << 16);
        unsigned hi32 = (unsigned)f2bf(a2) | ((unsigned)f2bf(a3) << 16);
        unsigned* dst = (unsigned*)&hl[lrow][lane * 4];
        dst[0] = lo32;
        dst[1] = hi32;
    }
    __syncthreads();

    if (wv == 0) {
        const int l15 = lane & 15, quad = lane >> 4;
        f32x4 acc[3] = {};
#pragma unroll
        for (int kc = 0; kc < NHID; kc += 32) {
            short8 a = *(const short8*)(&hl[l15][kc + quad * 8]);
#pragma unroll
            for (int nt = 0; nt < 3; nt++) {
                short8 b = *(const short8*)(w2t + (long)(nt * 16 + l15) * NHID + kc + quad * 8);
                acc[nt] = __builtin_amdgcn_mfma_f32_16x16x32_bf16(a, b, acc[nt], 0, 0, 0);
            }
        }
        const int prow0 = row0 + quad * 4;
#pragma unroll
        for (int nt = 0; nt < 3; nt++) {
            int col = nt * 16 + l15;
#pragma unroll
            for (int r = 0; r < 4; r++)
                p[(long)(prow0 + r) * P_STRIDE + col] = f2fp8(acc[nt][r]);
        }
    }
}

// ---------------------------------------------------------------------------
// K3: out = log_softmax(spmm(A, p) + b2).  One wave per row.
// p is fp8, 64 B rows (48 valid). e = lane>>4 (4 edge sub-groups),
// t = lane&15 (t<12 loads uint = cols 4t..4t+3).
// r12: 4-DEEP pipeline per sub-group (16 edges in flight per wave, was 8)
// — applying the r10-proven MLP lever to the same latency-bound pattern.
// ---------------------------------------------------------------------------
__global__ __launch_bounds__(256) void spmm2_kernel(const unsigned char* __restrict__ p,
                                                    const int* __restrict__ row_ptr,
                                                    const int* __restrict__ cols,
                                                    const float* __restrict__ vals,
                                                    const float* __restrict__ b2,
                                                    float* __restrict__ out) {
    int row = blockIdx.x * 4 + (threadIdx.x >> 6);
    if (row >= N_NODES) return;
    int lane = threadIdx.x & 63;
    int e = lane >> 4;          // edge sub-group 0..3
    int t = lane & 15;          // class chunk; t<12 active for loads
    int e0 = __builtin_amdgcn_readfirstlane(row_ptr[row]);
    int e1 = __builtin_amdgcn_readfirstlane(row_ptr[row + 1]);
    const unsigned toff = (unsigned)(t << 2);

    float a0 = 0.f, a1 = 0.f, a2 = 0.f, a3 = 0.f;
    if (e0 < e1) {
        const int em1 = e1 - 1;
        int i0 = e0 + e;      int i0c = i0 < e1 ? i0 : em1;
        int i1 = e0 + 4 + e;  int i1c = i1 < e1 ? i1 : em1;
        int i2 = e0 + 8 + e;  int i2c = i2 < e1 ? i2 : em1;
        int i3 = e0 + 12 + e; int i3c = i3 < e1 ? i3 : em1;
        int   ca = __builtin_nontemporal_load(cols + i0c);
        float va = __builtin_nontemporal_load(vals + i0c);
        int   cb = __builtin_nontemporal_load(cols + i1c);
        float vb = __builtin_nontemporal_load(vals + i1c);
        int   cc = __builtin_nontemporal_load(cols + i2c);
        float vc = __builtin_nontemporal_load(vals + i2c);
        int   cd = __builtin_nontemporal_load(cols + i3c);
        float vd = __builtin_nontemporal_load(vals + i3c);
        for (int j = e0; j < e1; j += 16) {
            int n0 = j + 16 + e; int n0c = n0 < e1 ? n0 : em1;
            int n1 = j + 20 + e; int n1c = n1 < e1 ? n1 : em1;
            int n2 = j + 24 + e; int n2c = n2 < e1 ? n2 : em1;
            int n3 = j + 28 + e; int n3c = n3 < e1 ? n3 : em1;
            int   ce = __builtin_nontemporal_load(cols + n0c);
            float ve = __builtin_nontemporal_load(vals + n0c);
            int   cf = __builtin_nontemporal_load(cols + n1c);
            float vf = __builtin_nontemporal_load(vals + n1c);
            int   cg = __builtin_nontemporal_load(cols + n2c);
            float vg = __builtin_nontemporal_load(vals + n2c);
            int   ch = __builtin_nontemporal_load(cols + n3c);
            float vh = __builtin_nontemporal_load(vals + n3c);
            unsigned q0 = (t < 12) ? *(const unsigned*)(p + (long)ca * P_STRIDE + toff) : 0u;
            unsigned q1 = (t < 12) ? *(const unsigned*)(p + (long)cb * P_STRIDE + toff) : 0u;
            unsigned q2 = (t < 12) ? *(const unsigned*)(p + (long)cc * P_STRIDE + toff) : 0u;
            unsigned q3 = (t < 12) ? *(const unsigned*)(p + (long)cd * P_STRIDE + toff) : 0u;
            float v0 = (j + e      < e1) ? va : 0.f;
            float v1 = (j + 4 + e  < e1) ? vb : 0.f;
            float v2 = (j + 8 + e  < e1) ? vc : 0.f;
            float v3 = (j + 12 + e < e1) ? vd : 0.f;
            f32x2 lo0 = __builtin_amdgcn_cvt_pk_f32_fp8((int)q0, false);
            f32x2 hi0 = __builtin_amdgcn_cvt_pk_f32_fp8((int)q0, true);
            f32x2 lo1 = __builtin_amdgcn_cvt_pk_f32_fp8((int)q1, false);
            f32x2 hi1 = __builtin_amdgcn_cvt_pk_f32_fp8((int)q1, true);
            f32x2 lo2 = __builtin_amdgcn_cvt_pk_f32_fp8((int)q2, false);
            f32x2 hi2 = __builtin_amdgcn_cvt_pk_f32_fp8((int)q2, true);
            f32x2 lo3 = __builtin_amdgcn_cvt_pk_f32_fp8((int)q3, false);
            f32x2 hi3 = __builtin_amdgcn_cvt_pk_f32_fp8((int)q3, true);
            a0 += v0 * lo0[0]; a1 += v0 * lo0[1]; a2 += v0 * hi0[0]; a3 += v0 * hi0[1];
            a0 += v1 * lo1[0]; a1 += v1 * lo1[1]; a2 += v1 * hi1[0]; a3 += v1 * hi1[1];
            a0 += v2 * lo2[0]; a1 += v2 * lo2[1]; a2 += v2 * hi2[0]; a3 += v2 * hi2[1];
            a0 += v3 * lo3[0]; a1 += v3 * lo3[1]; a2 += v3 * hi3[0]; a3 += v3 * hi3[1];
            ca = ce; va = ve; cb = cf; vb = vf;
            cc = cg; vc = vg; cd = ch; vd = vh;
        }
    }
    // fold the 4 edge sub-groups (lanes with same t share class columns)
    a0 += __shfl_xor(a0, 16); a1 += __shfl_xor(a1, 16);
    a2 += __shfl_xor(a2, 16); a3 += __shfl_xor(a3, 16);
    a0 += __shfl_xor(a0, 32); a1 += __shfl_xor(a1, 32);
    a2 += __shfl_xor(a2, 32); a3 += __shfl_xor(a3, 32);

    int c0 = 4 * t, c1 = 4 * t + 1, c2 = 4 * t + 2, c3 = 4 * t + 3;
    float l0 = (c0 < NCLASS) ? a0 + b2[c0] : -__builtin_inff();
    float l1 = (c1 < NCLASS) ? a1 + b2[c1] : -__builtin_inff();
    float l2 = (c2 < NCLASS) ? a2 + b2[c2] : -__builtin_inff();
    float l3 = (c3 < NCLASS) ? a3 + b2[c3] : -__builtin_inff();
    float m = fmaxf(fmaxf(l0, l1), fmaxf(l2, l3));
#pragma unroll
    for (int s = 8; s; s >>= 1) m = fmaxf(m, __shfl_xor(m, s));
    float esum = ((c0 < NCLASS) ? __expf(l0 - m) : 0.f)
               + ((c1 < NCLASS) ? __expf(l1 - m) : 0.f)
               + ((c2 < NCLASS) ? __expf(l2 - m) : 0.f)
               + ((c3 < NCLASS) ? __expf(l3 - m) : 0.f);
#pragma unroll
    for (int s = 8; s; s >>= 1) esum += __shfl_xor(esum, s);
    float lse = m + __logf(esum);
    if (e == 0) {
        long ob = (long)row * NCLASS;
        if (c0 < NCLASS) out[ob + c0] = l0 - lse;
        if (c1 < NCLASS) out[ob + c1] = l1 - lse;
        if (c2 < NCLASS) out[ob + c2] = l2 - lse;
        if (c3 < NCLASS) out[ob + c3] = l3 - lse;
    }
}

// ---------------------------------------------------------------------------
extern "C" void kernel_launch(void* const* d_in, const int* in_sizes, int n_in,
                              void* d_out, int out_size, void* d_ws, size_t ws_size,
                              hipStream_t stream) {
    const float* x        = (const float*)d_in[0];
    const int*   adj_rows = (const int*)  d_in[1];
    const int*   adj_cols = (const int*)  d_in[2];
    const float* adj_vals = (const float*)d_in[3];
    const float* w1       = (const float*)d_in[4];
    const float* b1       = (const float*)d_in[5];
    const float* w2       = (const float*)d_in[6];
    const float* b2       = (const float*)d_in[7];
    float* out = (float*)d_out;

    // workspace layout (within the proven 78 MB footprint):
    //   p  at 0x90000   (6.4 MB fp8 [N,64], spmm1g->spmm2; must NOT alias xw)
    //   xw at 0x3180000 (25.6 MB fp8 [N,256], gemm1->spmm1g)
    char* ws = (char*)d_ws;
    unsigned char*  w1q     = (unsigned char*) (ws);                  // 128 KB
    unsigned short* w2t     = (unsigned short*)(ws + 0x20000);        // 24 KB
    int*            row_ptr = (int*)           (ws + 0x26000);        // 0.4 MB
    unsigned char*  p       = (unsigned char*) (ws + 0x90000);        // 6.4 MB
    unsigned char*  xw      = (unsigned char*) (ws + 0x3180000);      // 25.6 MB

    prep_misc_kernel<<<392 + 512 + 48, 256, 0, stream>>>(adj_rows, w1, w2, row_ptr, w1q, w2t);
    gemm1_kernel<<<(N_NODES + 127) / 128, 512, 0, stream>>>(x, w1q, xw);
    spmm1g_kernel<<<N_NODES / 16, 256, 0, stream>>>(xw, row_ptr, adj_cols, adj_vals, b1, w2t, p);
    spmm2_kernel<<<(N_NODES + 3) / 4, 256, 0, stream>>>(p, row_ptr, adj_cols, adj_vals, b2, out);
}

// Round 13
// 531.675 us; speedup vs baseline: 1.0247x; 1.0035x over previous
//
#include <hip/hip_runtime.h>
#include <math.h>

#define N_NODES 100000
#define NNZ_E   3200000
#define NFEAT   512
#define NHID    256
#define NCLASS  41
#define NC_PAD  48     // w2t padded rows
#define P_STRIDE 64    // p row stride in bytes (fp8)

typedef __attribute__((ext_vector_type(8))) short   short8;   // 8 bf16 (4 VGPRs)
typedef __attribute__((ext_vector_type(4))) float   f32x4;
typedef __attribute__((ext_vector_type(2))) float   f32x2;

typedef __attribute__((address_space(1))) const unsigned int gu32;
typedef __attribute__((address_space(3))) unsigned int lu32;

// ---- bf16 helpers ----
__device__ __forceinline__ unsigned short f2bf(float f) {
    unsigned u = __builtin_bit_cast(unsigned, f);
    unsigned r = u + 0x7fffu + ((u >> 16) & 1u);   // RNE
    return (unsigned short)(r >> 16);
}
// ---- fp8 e4m3 helpers (OCP, native gfx950 cvt) ----
__device__ __forceinline__ unsigned char f2fp8(float f) {
    return (unsigned char)(__builtin_amdgcn_cvt_pk_fp8_f32(f, 0.f, 0, false) & 0xff);
}
__device__ __forceinline__ unsigned pk4(float a, float b, float c, float d) {
    unsigned u = __builtin_amdgcn_cvt_pk_fp8_f32(a, b, 0, false);
    return (unsigned)__builtin_amdgcn_cvt_pk_fp8_f32(c, d, (int)u, true);
}

// ---------------------------------------------------------------------------
// K0 (merged): CSR row_ptr + w1q fp8 + w2t bf16.
// Block ranges: [0,392) rowptr | [392,904) w1q | [904,952) w2t
// ---------------------------------------------------------------------------
__global__ __launch_bounds__(256) void prep_misc_kernel(const int* __restrict__ rows,
                                                        const float* __restrict__ w1,
                                                        const float* __restrict__ w2,
                                                        int* __restrict__ row_ptr,
                                                        unsigned char* __restrict__ w1q,
                                                        unsigned short* __restrict__ w2t) {
    int b = blockIdx.x;
    if (b < 392) {
        int r = b * 256 + threadIdx.x;
        if (r > N_NODES) return;
        int lo = 0, hi = NNZ_E;
        while (lo < hi) {
            int mid = (lo + hi) >> 1;
            if (rows[mid] < r) lo = mid + 1; else hi = mid;
        }
        row_ptr[r] = lo;
        return;
    }
    b -= 392;
    if (b < 512) {
        int tid = b * 256 + threadIdx.x;   // < 131072 exactly
        int n = tid >> 9, k = tid & 511;
        w1q[tid] = f2fp8(w1[k * NHID + n]);
        return;
    }
    b -= 512;
    {
        int t2 = b * 256 + threadIdx.x;    // < 12288 exactly
        int n = t2 >> 8, k = t2 & 255;
        w2t[t2] = (n < NCLASS) ? f2bf(w2[k * NCLASS + n]) : (unsigned short)0;
    }
}

// ---------------------------------------------------------------------------
// K1: fused quantize + GEMM:  xw = fp8(x) @ w1q  -> fp8 [N,256] row-major.
// 128-row x 256-col block tile, BK=64, 512 threads / 8 waves.
// r13 OCCUPANCY PROBE: hand-count put r12's live VGPR ~130 (>128) ->
// 1 block/CU (8 waves, 25%) -> no cross-block load/compute overlap,
// explaining ~2.6x over the 40us roofline and r5's neutral dbuf.
// Changes: (1) __launch_bounds__(512,4) caps VGPR at 128 (2 blocks/CU);
// (2) a/b LDS reads moved inside the ks loop (ab regs 32 -> 16) so the
// cap fits without spilling.  Everything else identical to r12.
// ---------------------------------------------------------------------------
__global__ __launch_bounds__(512, 4) void gemm1_kernel(const float* __restrict__ x,
                                                       const unsigned char* __restrict__ w1q,
                                                       unsigned char* __restrict__ xw) {
    __shared__ unsigned char As[8192];    // 128 rows x 64 B (swizzled)
    __shared__ unsigned char Bs[16384];   // 256 n    x 64 B (swizzled)

    const int tid  = threadIdx.x;
    const int wv   = tid >> 6;          // 0..7
    const int lane = tid & 63;
    const int l15  = lane & 15;
    const int quad = lane >> 4;
    const int wvM  = wv >> 2;           // 0..1  (row half)
    const int wvN  = wv & 3;            // 0..3  (col quarter)
    const int rb   = blockIdx.x * 128;

    const int ar = tid >> 2;            // 0..127
    const int aq = tid & 3;             // 0..3
    int arow = rb + ar; if (arow >= N_NODES) arow = N_NODES - 1;
    const float* asrc = x + (long)arow * NFEAT + aq * 16;
    unsigned char* adst0 = As + ar * 64 + (((2 * aq + 0) ^ (ar & 6)) * 8);
    unsigned char* adst1 = As + ar * 64 + (((2 * aq + 1) ^ (ar & 6)) * 8);

    const int bn0 = (wv * 2 + 0) * 16 + (lane >> 2);
    const int bn1 = (wv * 2 + 1) * 16 + (lane >> 2);
    const int bg0 = (lane & 3) ^ ((bn0 >> 1) & 3);
    const int bg1 = (lane & 3) ^ ((bn1 >> 1) & 3);
    const unsigned char* bsrc0 = w1q + (long)bn0 * NFEAT + bg0 * 16;
    const unsigned char* bsrc1 = w1q + (long)bn1 * NFEAT + bg1 * 16;

    f32x4 acc[4][4] = {};

    float4 fr0 = *(const float4*)(asrc);
    float4 fr1 = *(const float4*)(asrc + 4);
    float4 fr2 = *(const float4*)(asrc + 8);
    float4 fr3 = *(const float4*)(asrc + 12);

    for (int c = 0; c < 8; c++) {
        const int kc = c * 64;
        __builtin_amdgcn_global_load_lds((gu32*)(bsrc0 + kc), (lu32*)(Bs + (wv * 2 + 0) * 1024), 16, 0, 0);
        __builtin_amdgcn_global_load_lds((gu32*)(bsrc1 + kc), (lu32*)(Bs + (wv * 2 + 1) * 1024), 16, 0, 0);
        unsigned u0 = pk4(fr0.x, fr0.y, fr0.z, fr0.w);
        unsigned u1 = pk4(fr1.x, fr1.y, fr1.z, fr1.w);
        unsigned u2 = pk4(fr2.x, fr2.y, fr2.z, fr2.w);
        unsigned u3 = pk4(fr3.x, fr3.y, fr3.z, fr3.w);
        *(unsigned long long*)adst0 = (unsigned long long)u0 | ((unsigned long long)u1 << 32);
        *(unsigned long long*)adst1 = (unsigned long long)u2 | ((unsigned long long)u3 << 32);
        if (c < 7) {
            fr0 = *(const float4*)(asrc + kc + 64);
            fr1 = *(const float4*)(asrc + kc + 68);
            fr2 = *(const float4*)(asrc + kc + 72);
            fr3 = *(const float4*)(asrc + kc + 76);
        }
        __syncthreads();

#pragma unroll
        for (int ks = 0; ks < 2; ks++) {
            unsigned long long a[4], b[4];
#pragma unroll
            for (int mt = 0; mt < 4; mt++) {
                int row = wvM * 64 + mt * 16 + l15;
                int p8 = (ks * 4 + quad) ^ (row & 6);
                a[mt] = *(const unsigned long long*)(As + row * 64 + p8 * 8);
            }
#pragma unroll
            for (int nt = 0; nt < 4; nt++) {
                int nr = wvN * 64 + nt * 16 + l15;
                int p8 = (ks * 4 + quad) ^ (nr & 6);
                b[nt] = *(const unsigned long long*)(Bs + nr * 64 + p8 * 8);
            }
#pragma unroll
            for (int nt = 0; nt < 4; nt++)
#pragma unroll
                for (int mt = 0; mt < 4; mt++)
                    acc[mt][nt] = __builtin_amdgcn_mfma_f32_16x16x32_fp8_fp8(
                        (long)a[mt], (long)b[nt], acc[mt][nt], 0, 0, 0);
        }
        __syncthreads();
    }

#pragma unroll
    for (int mt = 0; mt < 4; mt++) {
        int row0 = rb + wvM * 64 + mt * 16 + quad * 4;
#pragma unroll
        for (int nt = 0; nt < 4; nt++) {
            int col = wvN * 64 + nt * 16 + l15;
#pragma unroll
            for (int r = 0; r < 4; r++) {
                int row = row0 + r;
                if (row < N_NODES)
                    xw[(long)row * NHID + col] = f2fp8(acc[mt][nt][r]);
            }
        }
    }
}

// ---------------------------------------------------------------------------
// K2 (fused spmm1 + gemm2): p = relu(spmm(A, xw) + b1) @ w2 -> fp8 [N,64].
// 16 rows/block (grid 6250, exact), 4 waves x 4 rows serial, LDS 8.4 KB.
// r10-proven inner loop (16-deep tier best; 32-deep regressed).
// Tiers: 16 -> 8 -> scalar. __launch_bounds__(256,4).
// Phase 2: wave 0 runs the 16-row MFMA tile.
// ---------------------------------------------------------------------------
__global__ __launch_bounds__(256, 4) void spmm1g_kernel(const unsigned char* __restrict__ xw,
                                                        const int* __restrict__ row_ptr,
                                                        const int* __restrict__ cols,
                                                        const float* __restrict__ vals,
                                                        const float* __restrict__ b1,
                                                        const unsigned short* __restrict__ w2t,
                                                        unsigned char* __restrict__ p) {
    __shared__ unsigned short hl[16][264];

    const int wv   = threadIdx.x >> 6;
    const int lane = threadIdx.x & 63;
    const int row0 = blockIdx.x * 16;
    const float4 bv = *(const float4*)(b1 + lane * 4);

    for (int r = 0; r < 4; r++) {
        const int lrow = wv * 4 + r;
        const int row  = row0 + lrow;              // always < N_NODES (exact grid)
        int e0 = row_ptr[row], e1 = row_ptr[row + 1];

        float a0 = 0.f, a1 = 0.f, a2 = 0.f, a3 = 0.f;
        for (int base = e0; base < e1; base += 64) {
            int   myc = 0;
            float myv = 0.f;
            int idx = base + lane;
            if (idx < e1) { myc = cols[idx]; myv = vals[idx]; }
            int cnt = e1 - base; if (cnt > 64) cnt = 64;
            int j = 0;
            // 16-deep tier: 16 gathers in flight
            for (; j + 16 <= cnt; j += 16) {
                int c[16]; float v[16];
#pragma unroll
                for (int u = 0; u < 16; u++) { c[u] = __shfl(myc, j + u); v[u] = __shfl(myv, j + u); }
                unsigned q[16];
#pragma unroll
                for (int u = 0; u < 16; u++) q[u] = *(const unsigned*)(xw + (long)c[u] * NHID + lane * 4);
#pragma unroll
                for (int u = 0; u < 16; u++) {
                    f32x2 lo = __builtin_amdgcn_cvt_pk_f32_fp8((int)q[u], false);
                    f32x2 hi = __builtin_amdgcn_cvt_pk_f32_fp8((int)q[u], true);
                    a0 += v[u] * lo[0];
                    a1 += v[u] * lo[1];
                    a2 += v[u] * hi[0];
                    a3 += v[u] * hi[1];
                }
            }
            // 8-deep tier
            for (; j + 8 <= cnt; j += 8) {
                int c[8]; float v[8];
#pragma unroll
                for (int u = 0; u < 8; u++) { c[u] = __shfl(myc, j + u); v[u] = __shfl(myv, j + u); }
                unsigned q[8];
#pragma unroll
                for (int u = 0; u < 8; u++) q[u] = *(const unsigned*)(xw + (long)c[u] * NHID + lane * 4);
#pragma unroll
                for (int u = 0; u < 8; u++) {
                    f32x2 lo = __builtin_amdgcn_cvt_pk_f32_fp8((int)q[u], false);
                    f32x2 hi = __builtin_amdgcn_cvt_pk_f32_fp8((int)q[u], true);
                    a0 += v[u] * lo[0];
                    a1 += v[u] * lo[1];
                    a2 += v[u] * hi[0];
                    a3 += v[u] * hi[1];
                }
            }
            // scalar tail
            for (; j < cnt; j++) {
                int   c = __shfl(myc, j);
                float v = __shfl(myv, j);
                unsigned q = *(const unsigned*)(xw + (long)c * NHID + lane * 4);
                f32x2 lo = __builtin_amdgcn_cvt_pk_f32_fp8((int)q, false);
                f32x2 hi = __builtin_amdgcn_cvt_pk_f32_fp8((int)q, true);
                a0 += v * lo[0];
                a1 += v * lo[1];
                a2 += v * hi[0];
                a3 += v * hi[1];
            }
        }
        a0 = fmaxf(a0 + bv.x, 0.f);
        a1 = fmaxf(a1 + bv.y, 0.f);
        a2 = fmaxf(a2 + bv.z, 0.f);
        a3 = fmaxf(a3 + bv.w, 0.f);
        unsigned lo32 = (unsigned)f2bf(a0) | ((unsigned)f2bf(a1) << 16);
        unsigned hi32 = (unsigned)f2bf(a2) | ((unsigned)f2bf(a3) << 16);
        unsigned* dst = (unsigned*)&hl[lrow][lane * 4];
        dst[0] = lo32;
        dst[1] = hi32;
    }
    __syncthreads();

    if (wv == 0) {
        const int l15 = lane & 15, quad = lane >> 4;
        f32x4 acc[3] = {};
#pragma unroll
        for (int kc = 0; kc < NHID; kc += 32) {
            short8 a = *(const short8*)(&hl[l15][kc + quad * 8]);
#pragma unroll
            for (int nt = 0; nt < 3; nt++) {
                short8 b = *(const short8*)(w2t + (long)(nt * 16 + l15) * NHID + kc + quad * 8);
                acc[nt] = __builtin_amdgcn_mfma_f32_16x16x32_bf16(a, b, acc[nt], 0, 0, 0);
            }
        }
        const int prow0 = row0 + quad * 4;
#pragma unroll
        for (int nt = 0; nt < 3; nt++) {
            int col = nt * 16 + l15;
#pragma unroll
            for (int r = 0; r < 4; r++)
                p[(long)(prow0 + r) * P_STRIDE + col] = f2fp8(acc[nt][r]);
        }
    }
}

// ---------------------------------------------------------------------------
// K3: out = log_softmax(spmm(A, p) + b2).  One wave per row.
// p is fp8, 64 B rows (48 valid). e = lane>>4 (4 edge sub-groups),
// t = lane&15 (t<12 loads uint = cols 4t..4t+3). 4-deep pipeline (r12).
// ---------------------------------------------------------------------------
__global__ __launch_bounds__(256) void spmm2_kernel(const unsigned char* __restrict__ p,
                                                    const int* __restrict__ row_ptr,
                                                    const int* __restrict__ cols,
                                                    const float* __restrict__ vals,
                                                    const float* __restrict__ b2,
                                                    float* __restrict__ out) {
    int row = blockIdx.x * 4 + (threadIdx.x >> 6);
    if (row >= N_NODES) return;
    int lane = threadIdx.x & 63;
    int e = lane >> 4;          // edge sub-group 0..3
    int t = lane & 15;          // class chunk; t<12 active for loads
    int e0 = __builtin_amdgcn_readfirstlane(row_ptr[row]);
    int e1 = __builtin_amdgcn_readfirstlane(row_ptr[row + 1]);
    const unsigned toff = (unsigned)(t << 2);

    float a0 = 0.f, a1 = 0.f, a2 = 0.f, a3 = 0.f;
    if (e0 < e1) {
        const int em1 = e1 - 1;
        int i0 = e0 + e;      int i0c = i0 < e1 ? i0 : em1;
        int i1 = e0 + 4 + e;  int i1c = i1 < e1 ? i1 : em1;
        int i2 = e0 + 8 + e;  int i2c = i2 < e1 ? i2 : em1;
        int i3 = e0 + 12 + e; int i3c = i3 < e1 ? i3 : em1;
        int   ca = __builtin_nontemporal_load(cols + i0c);
        float va = __builtin_nontemporal_load(vals + i0c);
        int   cb = __builtin_nontemporal_load(cols + i1c);
        float vb = __builtin_nontemporal_load(vals + i1c);
        int   cc = __builtin_nontemporal_load(cols + i2c);
        float vc = __builtin_nontemporal_load(vals + i2c);
        int   cd = __builtin_nontemporal_load(cols + i3c);
        float vd = __builtin_nontemporal_load(vals + i3c);
        for (int j = e0; j < e1; j += 16) {
            int n0 = j + 16 + e; int n0c = n0 < e1 ? n0 : em1;
            int n1 = j + 20 + e; int n1c = n1 < e1 ? n1 : em1;
            int n2 = j + 24 + e; int n2c = n2 < e1 ? n2 : em1;
            int n3 = j + 28 + e; int n3c = n3 < e1 ? n3 : em1;
            int   ce = __builtin_nontemporal_load(cols + n0c);
            float ve = __builtin_nontemporal_load(vals + n0c);
            int   cf = __builtin_nontemporal_load(cols + n1c);
            float vf = __builtin_nontemporal_load(vals + n1c);
            int   cg = __builtin_nontemporal_load(cols + n2c);
            float vg = __builtin_nontemporal_load(vals + n2c);
            int   ch = __builtin_nontemporal_load(cols + n3c);
            float vh = __builtin_nontemporal_load(vals + n3c);
            unsigned q0 = (t < 12) ? *(const unsigned*)(p + (long)ca * P_STRIDE + toff) : 0u;
            unsigned q1 = (t < 12) ? *(const unsigned*)(p + (long)cb * P_STRIDE + toff) : 0u;
            unsigned q2 = (t < 12) ? *(const unsigned*)(p + (long)cc * P_STRIDE + toff) : 0u;
            unsigned q3 = (t < 12) ? *(const unsigned*)(p + (long)cd * P_STRIDE + toff) : 0u;
            float v0 = (j + e      < e1) ? va : 0.f;
            float v1 = (j + 4 + e  < e1) ? vb : 0.f;
            float v2 = (j + 8 + e  < e1) ? vc : 0.f;
            float v3 = (j + 12 + e < e1) ? vd : 0.f;
            f32x2 lo0 = __builtin_amdgcn_cvt_pk_f32_fp8((int)q0, false);
            f32x2 hi0 = __builtin_amdgcn_cvt_pk_f32_fp8((int)q0, true);
            f32x2 lo1 = __builtin_amdgcn_cvt_pk_f32_fp8((int)q1, false);
            f32x2 hi1 = __builtin_amdgcn_cvt_pk_f32_fp8((int)q1, true);
            f32x2 lo2 = __builtin_amdgcn_cvt_pk_f32_fp8((int)q2, false);
            f32x2 hi2 = __builtin_amdgcn_cvt_pk_f32_fp8((int)q2, true);
            f32x2 lo3 = __builtin_amdgcn_cvt_pk_f32_fp8((int)q3, false);
            f32x2 hi3 = __builtin_amdgcn_cvt_pk_f32_fp8((int)q3, true);
            a0 += v0 * lo0[0]; a1 += v0 * lo0[1]; a2 += v0 * hi0[0]; a3 += v0 * hi0[1];
            a0 += v1 * lo1[0]; a1 += v1 * lo1[1]; a2 += v1 * hi1[0]; a3 += v1 * hi1[1];
            a0 += v2 * lo2[0]; a1 += v2 * lo2[1]; a2 += v2 * hi2[0]; a3 += v2 * hi2[1];
            a0 += v3 * lo3[0]; a1 += v3 * lo3[1]; a2 += v3 * hi3[0]; a3 += v3 * hi3[1];
            ca = ce; va = ve; cb = cf; vb = vf;
            cc = cg; vc = vg; cd = ch; vd = vh;
        }
    }
    // fold the 4 edge sub-groups (lanes with same t share class columns)
    a0 += __shfl_xor(a0, 16); a1 += __shfl_xor(a1, 16);
    a2 += __shfl_xor(a2, 16); a3 += __shfl_xor(a3, 16);
    a0 += __shfl_xor(a0, 32); a1 += __shfl_xor(a1, 32);
    a2 += __shfl_xor(a2, 32); a3 += __shfl_xor(a3, 32);

    int c0 = 4 * t, c1 = 4 * t + 1, c2 = 4 * t + 2, c3 = 4 * t + 3;
    float l0 = (c0 < NCLASS) ? a0 + b2[c0] : -__builtin_inff();
    float l1 = (c1 < NCLASS) ? a1 + b2[c1] : -__builtin_inff();
    float l2 = (c2 < NCLASS) ? a2 + b2[c2] : -__builtin_inff();
    float l3 = (c3 < NCLASS) ? a3 + b2[c3] : -__builtin_inff();
    float m = fmaxf(fmaxf(l0, l1), fmaxf(l2, l3));
#pragma unroll
    for (int s = 8; s; s >>= 1) m = fmaxf(m, __shfl_xor(m, s));
    float esum = ((c0 < NCLASS) ? __expf(l0 - m) : 0.f)
               + ((c1 < NCLASS) ? __expf(l1 - m) : 0.f)
               + ((c2 < NCLASS) ? __expf(l2 - m) : 0.f)
               + ((c3 < NCLASS) ? __expf(l3 - m) : 0.f);
#pragma unroll
    for (int s = 8; s; s >>= 1) esum += __shfl_xor(esum, s);
    float lse = m + __logf(esum);
    if (e == 0) {
        long ob = (long)row * NCLASS;
        if (c0 < NCLASS) out[ob + c0] = l0 - lse;
        if (c1 < NCLASS) out[ob + c1] = l1 - lse;
        if (c2 < NCLASS) out[ob + c2] = l2 - lse;
        if (c3 < NCLASS) out[ob + c3] = l3 - lse;
    }
}

// ---------------------------------------------------------------------------
extern "C" void kernel_launch(void* const* d_in, const int* in_sizes, int n_in,
                              void* d_out, int out_size, void* d_ws, size_t ws_size,
                              hipStream_t stream) {
    const float* x        = (const float*)d_in[0];
    const int*   adj_rows = (const int*)  d_in[1];
    const int*   adj_cols = (const int*)  d_in[2];
    const float* adj_vals = (const float*)d_in[3];
    const float* w1       = (const float*)d_in[4];
    const float* b1       = (const float*)d_in[5];
    const float* w2       = (const float*)d_in[6];
    const float* b2       = (const float*)d_in[7];
    float* out = (float*)d_out;

    // workspace layout (within the proven 78 MB footprint):
    //   p  at 0x90000   (6.4 MB fp8 [N,64], spmm1g->spmm2; must NOT alias xw)
    //   xw at 0x3180000 (25.6 MB fp8 [N,256], gemm1->spmm1g)
    char* ws = (char*)d_ws;
    unsigned char*  w1q     = (unsigned char*) (ws);                  // 128 KB
    unsigned short* w2t     = (unsigned short*)(ws + 0x20000);        // 24 KB
    int*            row_ptr = (int*)           (ws + 0x26000);        // 0.4 MB
    unsigned char*  p       = (unsigned char*) (ws + 0x90000);        // 6.4 MB
    unsigned char*  xw      = (unsigned char*) (ws + 0x3180000);      // 25.6 MB

    prep_misc_kernel<<<392 + 512 + 48, 256, 0, stream>>>(adj_rows, w1, w2, row_ptr, w1q, w2t);
    gemm1_kernel<<<(N_NODES + 127) / 128, 512, 0, stream>>>(x, w1q, xw);
    spmm1g_kernel<<<N_NODES / 16, 256, 0, stream>>>(xw, row_ptr, adj_cols, adj_vals, b1, w2t, p);
    spmm2_kernel<<<(N_NODES + 3) / 4, 256, 0, stream>>>(p, row_ptr, adj_cols, adj_vals, b2, out);
}